// Round 2
// baseline (10735.852 us; speedup 1.0000x reference)
//
#include <hip/hip_runtime.h>

// Persistent batched-GRU kernel for MI355X (gfx950), round 11.
// r10 post-mortem: VALU diet worked (VALU 3170->2236 cyc/step) but the
// j-phase split halved MFMA ILP (3 chains/phase -> dep stalls, busy 79->60%)
// and doubled A-frag LDS reads (bank conflicts 2.7e8->4.7e8). Round-11:
//  - restore r9's unified K-loop: all 6 acc chains (3 gates x 2 j) in ONE
//    pass over the 8 A-frags (single ds_read_b128 per ks).
//  - keep the VALU diet: pre-scaled weights (exp2 folding), bias-preloaded
//    accumulators, rcp(1+exp2) gates, cvt_pk_bf16 publishes.
//  - zero-cost tail overlap: j1's ks=6,7 MFMAs deferred past j0's chain
//    end; j0 gate elements interleaved between them (no extra registers,
//    no sched_group_barrier hints).
// Register budget is the binding constraint: 192 (weights) + 24 (acc) +
// ~40 working = ~256/wave at 2 waves/SIMD. Do not add register state.

#define B_TOTAL 16384
#define T_LEN   1024
#define M_ROWS  16
#define NBLOCKS (B_TOTAL / M_ROWS)      // 1024 blocks; ~4 sequential per CU
#define NTHREADS 512                    // 8 waves
#define LDSW    264                     // h row stride in shorts
#define TCH     32                      // t-chunk length
#define NCH     (T_LEN / TCH)           // 32
#define XSTR    20                      // x_buf t-row stride (floats)
#define OSTR    33                      // out_buf row stride (floats)

typedef short short8 __attribute__((ext_vector_type(8)));
typedef float f32x4  __attribute__((ext_vector_type(4)));

__device__ unsigned short g_wsw[196608];   // swizzled, PRE-SCALED bf16 W_hh

__device__ __forceinline__ unsigned short f2b(float f) {
  unsigned u = __builtin_bit_cast(unsigned, f);
  u += 0x7fffu + ((u >> 16) & 1u);
  return (unsigned short)(u >> 16);
}
__device__ __forceinline__ unsigned cvt_pk_bf16(float lo, float hi) {
  unsigned r;
  asm("v_cvt_pk_bf16_f32 %0, %1, %2" : "=v"(r) : "v"(lo), "v"(hi));
  return r;
}
// sum over a 16-lane DPP row; result valid in the LAST lane (r16==15)
__device__ __forceinline__ float dpp_red16(float v) {
  int x = __builtin_bit_cast(int, v);
  v += __builtin_bit_cast(float, __builtin_amdgcn_update_dpp(0, x, 0x118, 0xF, 0xF, true)); // row_shr:8
  x = __builtin_bit_cast(int, v);
  v += __builtin_bit_cast(float, __builtin_amdgcn_update_dpp(0, x, 0x114, 0xF, 0xF, true)); // row_shr:4
  x = __builtin_bit_cast(int, v);
  v += __builtin_bit_cast(float, __builtin_amdgcn_update_dpp(0, x, 0x112, 0xF, 0xF, true)); // row_shr:2
  x = __builtin_bit_cast(int, v);
  v += __builtin_bit_cast(float, __builtin_amdgcn_update_dpp(0, x, 0x111, 0xF, 0xF, true)); // row_shr:1
  return v;
}
// barrier draining LDS only (no vmcnt(0): global stores stay in flight)
__device__ __forceinline__ void barrier_lgkm() {
  asm volatile("s_waitcnt lgkmcnt(0)\n\ts_barrier" ::: "memory");
}

// Swizzle W_hh (768x256 f32 row-major) into fragment-major bf16, pre-scaled:
// rows 0..511 (r,z gates) * -log2e ; rows 512..767 (n gate) * 2*log2e.
__global__ void prep_w(const float* __restrict__ w_hh) {
  int tid  = blockIdx.x * 256 + threadIdx.x;     // 196608 total
  int e    = tid & 7;
  int lane = (tid >> 3) & 63;
  int ks   = (tid >> 9) & 7;
  int nt   = tid >> 12;
  int row  = nt * 16 + (lane & 15);
  int col  = ks * 32 + (lane >> 4) * 8 + e;
  float s  = (row < 512) ? -1.44269504f : 2.88539008f;
  g_wsw[tid] = f2b(w_hh[row * 256 + col] * s);
}

// one gate element: J=col-tile, I=row-within-quad; A0/A1/A2 = acc scalars
#define GATE_EL(J, I, A0, A1, A2)                                              \
  {                                                                            \
    float t_r = __builtin_fmaf(xv[I], swr[J], (A0));                           \
    float rg  = __builtin_amdgcn_rcpf(1.0f + __builtin_amdgcn_exp2f(t_r));     \
    float t_z = __builtin_fmaf(xv[I], swz[J], (A1));                           \
    float zg  = __builtin_amdgcn_rcpf(1.0f + __builtin_amdgcn_exp2f(t_z));     \
    float t_n = __builtin_fmaf(xv[I], swn[J], sbni[J]);                        \
    float yn  = __builtin_fmaf(rg, (A2), t_n);                                 \
    float rn  = __builtin_amdgcn_rcpf(1.0f + __builtin_amdgcn_exp2f(yn));      \
    float ng  = __builtin_fmaf(-2.0f, rn, 1.0f);                               \
    float hn  = __builtin_fmaf(zg, h_reg[J][I] - ng, ng);                      \
    h_reg[J][I] = hn;                                                          \
    vo[I] += fmaxf(hn, 0.0f) * wo[J];                                          \
  }

// publish rows (q*4+I0, q*4+I0+1) of column cc[J] as one packed bf16 pair
#define PUB_PAIR(J, I0)                                                        \
  {                                                                            \
    unsigned pk = cvt_pk_bf16(h_reg[J][I0], h_reg[J][(I0) + 1]);               \
    hwp[(q * 4 + (I0)) * LDSW + cc[J]]     = (unsigned short)pk;               \
    hwp[(q * 4 + (I0) + 1) * LDSW + cc[J]] = (unsigned short)(pk >> 16);       \
  }

__global__ __launch_bounds__(NTHREADS, 2) void gru_kernel(
    const float* __restrict__ x,
    const float* __restrict__ w_ih,
    const float* __restrict__ b_ih,
    const float* __restrict__ b_hh,
    const float* __restrict__ w_out,
    const float* __restrict__ b_out,
    float* __restrict__ out)
{
  __shared__ unsigned short h_lds[2][M_ROWS * LDSW];  // 2 x 8.25 KB
  __shared__ float x_buf[2][TCH * XSTR];              // 2 x 2.5 KB, [t][row]
  __shared__ float out_buf[2][M_ROWS * OSTR];         // 2 x 2.06 KB, [row][t]
  __shared__ float op[2][8][M_ROWS];                  // 2 x 0.5 KB

  const int tid  = threadIdx.x;
  const int w    = tid >> 6;        // wave 0..7
  const int lane = tid & 63;
  const int r16  = lane & 15;
  const int q    = lane >> 4;
  const long base = (long)blockIdx.x * M_ROWS;

  for (int i = tid; i < M_ROWS * LDSW; i += NTHREADS) h_lds[0][i] = 0;  // h0 = 0

  // ---- resident weights: 48 frags (3 gates x 2 col-tiles x 8 k-steps) ----
  short8 wr[3][2][8];
#pragma unroll
  for (int g = 0; g < 3; ++g)
#pragma unroll
    for (int j = 0; j < 2; ++j)
#pragma unroll
      for (int ks = 0; ks < 8; ++ks)
        wr[g][j][ks] = *(const short8*)&g_wsw[(((g * 16 + w * 2 + j) * 8 + ks) * 64 + lane) * 8];

  // per-lane constants for cols c(j) = w*32 + j*16 + r16, pre-scaled by the
  // exp2 factors: r,z: -log2e ; n: +2*log2e
  const float C1 = 1.44269504f;
  float swr[2], swz[2], swn[2], sbr[2], sbz[2], sbni[2], sbnh[2], wo[2];
  int cc[2];
#pragma unroll
  for (int j = 0; j < 2; ++j) {
    int c = w * 32 + j * 16 + r16;
    cc[j]   = c;
    swr[j]  = -C1 * w_ih[c];
    swz[j]  = -C1 * w_ih[256 + c];
    swn[j]  = 2.0f * C1 * w_ih[512 + c];
    sbr[j]  = -C1 * (b_ih[c] + b_hh[c]);
    sbz[j]  = -C1 * (b_ih[256 + c] + b_hh[256 + c]);
    sbni[j] = 2.0f * C1 * b_ih[512 + c];
    sbnh[j] = 2.0f * C1 * b_hh[512 + c];
    wo[j]   = w_out[c];
  }
  const float bo = b_out[0];
  const f32x4 zero4 = {0.f, 0.f, 0.f, 0.f};

  float h_reg[2][4];                // C layout: row = q*4 + i, col = cc[j]
#pragma unroll
  for (int j = 0; j < 2; ++j)
#pragma unroll
    for (int i = 0; i < 4; ++i) h_reg[j][i] = 0.0f;

  const int xr = tid >> 5;          // 0..15: staging row
  const int xt = tid & 31;          // 0..31: staging t-slot

  // prefill x chunk 0 (transposed [t][row])
  x_buf[0][xt * XSTR + xr] = x[(base + xr) * T_LEN + xt];

  barrier_lgkm();

#pragma unroll 1
  for (int t = 0; t < T_LEN; ++t) {
    const int tr = t & (TCH - 1);
    const int tc = t >> 5;
    const int xp = tc & 1;
    const int rp = t & 1;

    // ---- finalize out(t-1): op[(t-1)&1] stable since last barrier ----
    if (t > 0 && tid < M_ROWS) {
      float o = bo;
#pragma unroll
      for (int ww = 0; ww < 8; ++ww) o += op[(t - 1) & 1][ww][tid];
      out_buf[((t - 1) >> 5) & 1][tid * OSTR + ((t - 1) & 31)] = o;
    }

    const unsigned short* ar = &h_lds[rp][r16 * LDSW + q * 8];
    unsigned short* hwp = &h_lds[rp ^ 1][0];
    f32x4 xv = *(const f32x4*)&x_buf[xp][tr * XSTR + q * 4];
    f32x4 vo = zero4;

    // ---- unified K-loop: 6 acc chains, one pass over A-frags ----
    // j1 chains stop at ks=5; their ks=6,7 MFMAs are deferred into the
    // gate tail so j0's gate VALU can interleave with them.
    f32x4 aA0 = {sbr[0], sbr[0], sbr[0], sbr[0]};
    f32x4 aA1 = {sbz[0], sbz[0], sbz[0], sbz[0]};
    f32x4 aA2 = {sbnh[0], sbnh[0], sbnh[0], sbnh[0]};
    f32x4 aB0 = {sbr[1], sbr[1], sbr[1], sbr[1]};
    f32x4 aB1 = {sbz[1], sbz[1], sbz[1], sbz[1]};
    f32x4 aB2 = {sbnh[1], sbnh[1], sbnh[1], sbnh[1]};
#pragma unroll
    for (int ks = 0; ks < 6; ++ks) {
      short8 a = *(const short8*)(ar + ks * 32);
      aA0 = __builtin_amdgcn_mfma_f32_16x16x32_bf16(a, wr[0][0][ks], aA0, 0, 0, 0);
      aB0 = __builtin_amdgcn_mfma_f32_16x16x32_bf16(a, wr[0][1][ks], aB0, 0, 0, 0);
      aA1 = __builtin_amdgcn_mfma_f32_16x16x32_bf16(a, wr[1][0][ks], aA1, 0, 0, 0);
      aB1 = __builtin_amdgcn_mfma_f32_16x16x32_bf16(a, wr[1][1][ks], aB1, 0, 0, 0);
      aA2 = __builtin_amdgcn_mfma_f32_16x16x32_bf16(a, wr[2][0][ks], aA2, 0, 0, 0);
      aB2 = __builtin_amdgcn_mfma_f32_16x16x32_bf16(a, wr[2][1][ks], aB2, 0, 0, 0);
    }
    short8 a6 = *(const short8*)(ar + 6 * 32);
    short8 a7 = *(const short8*)(ar + 7 * 32);
    // finish j0 chains (ready for gates)
    aA0 = __builtin_amdgcn_mfma_f32_16x16x32_bf16(a6, wr[0][0][6], aA0, 0, 0, 0);
    aA1 = __builtin_amdgcn_mfma_f32_16x16x32_bf16(a6, wr[1][0][6], aA1, 0, 0, 0);
    aA2 = __builtin_amdgcn_mfma_f32_16x16x32_bf16(a6, wr[2][0][6], aA2, 0, 0, 0);
    aA0 = __builtin_amdgcn_mfma_f32_16x16x32_bf16(a7, wr[0][0][7], aA0, 0, 0, 0);
    aA1 = __builtin_amdgcn_mfma_f32_16x16x32_bf16(a7, wr[1][0][7], aA1, 0, 0, 0);
    aA2 = __builtin_amdgcn_mfma_f32_16x16x32_bf16(a7, wr[2][0][7], aA2, 0, 0, 0);

    // ---- j0 gates interleaved with j1's deferred tail MFMAs ----
    GATE_EL(0, 0, aA0[0], aA1[0], aA2[0]);
    aB0 = __builtin_amdgcn_mfma_f32_16x16x32_bf16(a6, wr[0][1][6], aB0, 0, 0, 0);
    GATE_EL(0, 1, aA0[1], aA1[1], aA2[1]);
    aB1 = __builtin_amdgcn_mfma_f32_16x16x32_bf16(a6, wr[1][1][6], aB1, 0, 0, 0);
    PUB_PAIR(0, 0);
    aB2 = __builtin_amdgcn_mfma_f32_16x16x32_bf16(a6, wr[2][1][6], aB2, 0, 0, 0);
    GATE_EL(0, 2, aA0[2], aA1[2], aA2[2]);
    aB0 = __builtin_amdgcn_mfma_f32_16x16x32_bf16(a7, wr[0][1][7], aB0, 0, 0, 0);
    GATE_EL(0, 3, aA0[3], aA1[3], aA2[3]);
    aB1 = __builtin_amdgcn_mfma_f32_16x16x32_bf16(a7, wr[1][1][7], aB1, 0, 0, 0);
    PUB_PAIR(0, 2);
    aB2 = __builtin_amdgcn_mfma_f32_16x16x32_bf16(a7, wr[2][1][7], aB2, 0, 0, 0);

    // ---- j1 gates + publish ----
    GATE_EL(1, 0, aB0[0], aB1[0], aB2[0]);
    GATE_EL(1, 1, aB0[1], aB1[1], aB2[1]);
    PUB_PAIR(1, 0);
    GATE_EL(1, 2, aB0[2], aB1[2], aB2[2]);
    GATE_EL(1, 3, aB0[3], aB1[3], aB2[3]);
    PUB_PAIR(1, 2);

    // ---- out partial: 16-lane DPP reduce, lane 15 holds the sum ----
#pragma unroll
    for (int i = 0; i < 4; ++i) vo[i] = dpp_red16(vo[i]);
    if (r16 == 15) {
#pragma unroll
      for (int i = 0; i < 4; ++i) op[t & 1][w][q * 4 + i] = vo[i];
    }

    // ---- chunk refill/flush (once per 32 steps, at tr==1) ----
    if (tr == 1) {
      if (tc + 1 < NCH)
        x_buf[xp ^ 1][xt * XSTR + xr] = x[(base + xr) * T_LEN + (tc + 1) * TCH + xt];
      if (tc > 0)
        out[(base + xr) * T_LEN + (tc - 1) * TCH + xt] =
            out_buf[(tc - 1) & 1][xr * OSTR + xt];
    }

    barrier_lgkm();
  }

  // ---- epilogue: finalize step T-1, flush last chunk ----
  if (tid < M_ROWS) {
    float o = bo;
#pragma unroll
    for (int ww = 0; ww < 8; ++ww) o += op[(T_LEN - 1) & 1][ww][tid];
    out_buf[((T_LEN - 1) >> 5) & 1][tid * OSTR + (TCH - 1)] = o;
  }
  barrier_lgkm();
  out[(base + xr) * T_LEN + (NCH - 1) * TCH + xt] =
      out_buf[(NCH - 1) & 1][xr * OSTR + xt];
}

extern "C" void kernel_launch(void* const* d_in, const int* in_sizes, int n_in,
                              void* d_out, int out_size, void* d_ws, size_t ws_size,
                              hipStream_t stream) {
  const float* x     = (const float*)d_in[0];
  const float* w_ih  = (const float*)d_in[1];
  const float* w_hh  = (const float*)d_in[2];
  const float* b_ih  = (const float*)d_in[3];
  const float* b_hh  = (const float*)d_in[4];
  const float* w_out = (const float*)d_in[5];
  const float* b_out = (const float*)d_in[6];
  float* out = (float*)d_out;

  prep_w<<<768, 256, 0, stream>>>(w_hh);
  gru_kernel<<<NBLOCKS, NTHREADS, 0, stream>>>(x, w_ih, b_ih, b_hh, w_out, b_out, out);
}

// Round 3
// 7942.206 us; speedup vs baseline: 1.3517x; 1.3517x over previous
//
#include <hip/hip_runtime.h>

// Persistent batched-GRU kernel for MI355X (gfx950), round 12.
// r10/r11 post-mortem: VALU diet cut busy cycles but wall rose -> the step is
// serialization-bound (gates wait on MFMAs, next MFMAs wait on barrier), not
// VALU-count bound. Round-12: TWO-GROUP IN-WAVE PIPELINE.
//   Block owns 32 batch rows = groups P (rows 0-15) and Q (rows 16-31).
//   512 blocks x 512 threads. Weights are per-column -> shared by both groups.
//   Per barrier interval each wave runs MFMA for one group interleaved with
//   gate elements of the OTHER group (fully independent work) -> matrix pipe
//   and VALU overlap instead of alternating.
//     pre:  A0:   MFMA(P,0)                                | barrier
//     loop: B(s): MFMA(Q,s)   + gates(P,s)   + fin(P,s-1)  | barrier
//           A(s+1): MFMA(P,s+1)+ gates(Q,s)  + fin(Q,s-1)  | barrier
//     post: B(1023), epilogue gates(Q,1023), final fins.
//   Register budget: z_j1 + n_j1 weight frags moved to LDS (128 KB,
//   lane-contiguous -> conflict-free) keeping 128 weight VGPRs; two acc sets
//   (48) + h_reg f32 (16) + consts fit ~250/256.
// Gate math is r9's PROVEN formulas verbatim (expf, f2b, f32 h carry) -- the
// diet is reverted (two rounds showed it trades busy for idle).

#define B_TOTAL 16384
#define T_LEN   1024
#define GRPROWS 16
#define M_ROWS  32
#define NBLOCKS (B_TOTAL / M_ROWS)      // 512 blocks; 2 sequential per CU
#define NTHREADS 512                    // 8 waves
#define LDSW    264                     // h row stride in shorts

typedef short short8 __attribute__((ext_vector_type(8)));
typedef float f32x4  __attribute__((ext_vector_type(4)));

__device__ unsigned short g_wsw[196608];   // swizzled bf16 W_hh (384 KB)

__device__ __forceinline__ unsigned short f2b(float f) {
  unsigned u = __builtin_bit_cast(unsigned, f);
  u += 0x7fffu + ((u >> 16) & 1u);
  return (unsigned short)(u >> 16);
}
__device__ __forceinline__ float fast_sig(float x) {
  return __builtin_amdgcn_rcpf(1.0f + __expf(-x));
}
__device__ __forceinline__ float fast_tanh(float x) {
  return 2.0f * fast_sig(2.0f * x) - 1.0f;
}
// sum over a 16-lane DPP row; result valid in the LAST lane (r16==15)
__device__ __forceinline__ float dpp_red16(float v) {
  int x = __builtin_bit_cast(int, v);
  v += __builtin_bit_cast(float, __builtin_amdgcn_update_dpp(0, x, 0x118, 0xF, 0xF, true)); // row_shr:8
  x = __builtin_bit_cast(int, v);
  v += __builtin_bit_cast(float, __builtin_amdgcn_update_dpp(0, x, 0x114, 0xF, 0xF, true)); // row_shr:4
  x = __builtin_bit_cast(int, v);
  v += __builtin_bit_cast(float, __builtin_amdgcn_update_dpp(0, x, 0x112, 0xF, 0xF, true)); // row_shr:2
  x = __builtin_bit_cast(int, v);
  v += __builtin_bit_cast(float, __builtin_amdgcn_update_dpp(0, x, 0x111, 0xF, 0xF, true)); // row_shr:1
  return v;
}
// barrier draining LDS only (no vmcnt(0): global stores stay in flight)
__device__ __forceinline__ void barrier_lgkm() {
  asm volatile("s_waitcnt lgkmcnt(0)\n\ts_barrier" ::: "memory");
}

// Swizzle W_hh (768x256 f32 row-major) into fragment-major bf16 (r9 layout,
// NO pre-scaling):
// dst[((nt*8 + ks)*64 + lane)*8 + e] = bf16(W[nt*16 + (lane&15)][ks*32 + (lane>>4)*8 + e])
__global__ void prep_w(const float* __restrict__ w_hh) {
  int tid  = blockIdx.x * 256 + threadIdx.x;     // 196608 total
  int e    = tid & 7;
  int lane = (tid >> 3) & 63;
  int ks   = (tid >> 9) & 7;
  int nt   = tid >> 12;
  int row  = nt * 16 + (lane & 15);
  int col  = ks * 32 + (lane >> 4) * 8 + e;
  g_wsw[tid] = f2b(w_hh[row * 256 + col]);
}

#define MF(A, B, C) __builtin_amdgcn_mfma_f32_16x16x32_bf16((A), (B), (C), 0, 0, 0)

// one K-step for acc-set P## (6 chains): 4 register B-frags + 2 LDS B-frags,
// EXTRA = interleaved gate work for the other group
#define KSTEP(P, AR, KS, EXTRA)  {                                             \
    short8 a_  = *(const short8*)((AR) + (KS)*32);                             \
    short8 z1_ = *(const short8*)&w_lds[wz1b + (KS)*512];                      \
    short8 n1_ = *(const short8*)&w_lds[wn1b + (KS)*512];                      \
    P##00 = MF(a_, wrr0[KS], P##00);                                           \
    P##01 = MF(a_, wrr1[KS], P##01);                                           \
    P##10 = MF(a_, wrz0[KS], P##10);                                           \
    P##11 = MF(a_, z1_,      P##11);                                           \
    P##20 = MF(a_, wrn0[KS], P##20);                                           \
    P##21 = MF(a_, n1_,      P##21);                                           \
    EXTRA                                                                      \
  }

// one gate element, r9 math verbatim. AC=acc prefix, HR=h_reg, XV=x vec,
// VO=out accum, HG=h_lds group index, J=col-tile, I=row-in-quad
#define GEL(AC, HR, XV, VO, HG, J, I) {                                        \
    float rg_ = fast_sig(AC##0##J[I] + XV[I]*wi_r[J] + bt_r[J]);               \
    float zg_ = fast_sig(AC##1##J[I] + XV[I]*wi_z[J] + bt_z[J]);               \
    float ng_ = fast_tanh(XV[I]*wi_n[J] + bih_n[J] + rg_*(AC##2##J[I] + bhh_n[J])); \
    float hn_ = (1.0f - zg_)*ng_ + zg_*HR[J][I];                               \
    HR[J][I] = hn_;                                                            \
    h_lds[HG][hwb[J] + (I)*LDSW] = f2b(hn_);                                   \
    VO[I] += fmaxf(hn_, 0.0f)*wo[J];                                           \
  }

#define VORED(VO, G, S) {                                                      \
    _Pragma("unroll") for (int i_ = 0; i_ < 4; ++i_) VO[i_] = dpp_red16(VO[i_]); \
    if (r16 == 15) {                                                           \
      _Pragma("unroll") for (int i_ = 0; i_ < 4; ++i_)                         \
        op[G][(S)&1][w][q*4 + i_] = VO[i_];                                    \
    } }

// finalize out(G, S): 16 threads starting at TLO sum 8 wave partials + store
#define FIN(G, S, TLO)                                                         \
  if (tid >= (TLO) && tid < (TLO) + 16) {                                      \
    float o_ = bo;                                                             \
    _Pragma("unroll") for (int ww_ = 0; ww_ < 8; ++ww_)                        \
      o_ += op[G][(S)&1][ww_][tid - (TLO)];                                    \
    out[(base + (G)*GRPROWS + (tid - (TLO)))*T_LEN + (S)] = o_;                \
  }

#define ACCZERO(P) P##00 = zero4; P##01 = zero4; P##10 = zero4;                \
                   P##11 = zero4; P##20 = zero4; P##21 = zero4;

#define XLOAD(XV, G, S) {                                                      \
    _Pragma("unroll") for (int i_ = 0; i_ < 4; ++i_)                           \
      XV[i_] = x[(base + (G)*GRPROWS + q*4 + i_)*T_LEN + (S)];                 \
  }

__global__ __launch_bounds__(NTHREADS, 2) void gru_kernel(
    const float* __restrict__ x,
    const float* __restrict__ w_ih,
    const float* __restrict__ b_ih,
    const float* __restrict__ b_hh,
    const float* __restrict__ w_out,
    const float* __restrict__ b_out,
    float* __restrict__ out)
{
  __shared__ unsigned short h_lds[2][GRPROWS * LDSW];  // [group], 16.5 KB
  __shared__ unsigned short w_lds[16 * 8 * 512];       // z_j1/n_j1 frags, 128 KB
  __shared__ float op[2][2][8][GRPROWS];               // [group][phase][wave][row], 4 KB

  const int tid  = threadIdx.x;
  const int w    = tid >> 6;        // wave 0..7
  const int lane = tid & 63;
  const int r16  = lane & 15;
  const int q    = lane >> 4;
  const long base = (long)blockIdx.x * M_ROWS;

  for (int i = tid; i < 2 * GRPROWS * LDSW; i += NTHREADS) h_lds[0][i] = 0;  // h0 = 0 (both groups)

  // ---- stage z_j1 (gsel 0) and n_j1 (gsel 1) frags into LDS ----
  const int wz1b = ((w*2 + 0)*8)*512 + lane*8;
  const int wn1b = ((w*2 + 1)*8)*512 + lane*8;
#pragma unroll
  for (int gsel = 0; gsel < 2; ++gsel)
#pragma unroll
    for (int ks = 0; ks < 8; ++ks)
      *(short8*)&w_lds[((w*2 + gsel)*8 + ks)*512 + lane*8] =
        *(const short8*)&g_wsw[((((gsel + 1)*16 + w*2 + 1)*8 + ks)*64 + lane)*8];

  // ---- register-resident frags: r_j0, r_j1, z_j0, n_j0 (128 VGPR) ----
  short8 wrr0[8], wrr1[8], wrz0[8], wrn0[8];
#pragma unroll
  for (int ks = 0; ks < 8; ++ks) {
    wrr0[ks] = *(const short8*)&g_wsw[(((0*16 + w*2 + 0)*8 + ks)*64 + lane)*8];
    wrr1[ks] = *(const short8*)&g_wsw[(((0*16 + w*2 + 1)*8 + ks)*64 + lane)*8];
    wrz0[ks] = *(const short8*)&g_wsw[(((1*16 + w*2 + 0)*8 + ks)*64 + lane)*8];
    wrn0[ks] = *(const short8*)&g_wsw[(((2*16 + w*2 + 0)*8 + ks)*64 + lane)*8];
  }

  // per-lane constants for cols c(j) = w*32 + j*16 + r16 (r9 verbatim)
  float wi_r[2], wi_z[2], wi_n[2], bt_r[2], bt_z[2], bih_n[2], bhh_n[2], wo[2];
  int cc[2], hwb[2];
#pragma unroll
  for (int j = 0; j < 2; ++j) {
    int c = w*32 + j*16 + r16;
    cc[j]    = c;
    hwb[j]   = (q*4)*LDSW + c;
    wi_r[j]  = w_ih[c];
    wi_z[j]  = w_ih[256 + c];
    wi_n[j]  = w_ih[512 + c];
    bt_r[j]  = b_ih[c]       + b_hh[c];
    bt_z[j]  = b_ih[256 + c] + b_hh[256 + c];
    bih_n[j] = b_ih[512 + c];
    bhh_n[j] = b_hh[512 + c];
    wo[j]    = w_out[c];
  }
  const float bo = b_out[0];
  const f32x4 zero4 = {0.f, 0.f, 0.f, 0.f};

  float hP[2][4], hQ[2][4];        // f32 h carry, both groups
#pragma unroll
  for (int j = 0; j < 2; ++j)
#pragma unroll
    for (int i = 0; i < 4; ++i) { hP[j][i] = 0.0f; hQ[j][i] = 0.0f; }

  const unsigned short* arP = &h_lds[0][r16*LDSW + q*8];
  const unsigned short* arQ = &h_lds[1][r16*LDSW + q*8];

  // acc sets: aP## built in A-intervals / consumed in B; aQ## vice versa
  f32x4 aP00, aP01, aP10, aP11, aP20, aP21;
  f32x4 aQ00, aQ01, aQ10, aQ11, aQ20, aQ21;

  barrier_lgkm();   // h zeros + w_lds staged

  // ---- pre-loop interval A0: MFMA(P, 0) only ----
  {
    ACCZERO(aP)
    KSTEP(aP, arP, 0, ) KSTEP(aP, arP, 1, ) KSTEP(aP, arP, 2, ) KSTEP(aP, arP, 3, )
    KSTEP(aP, arP, 4, ) KSTEP(aP, arP, 5, ) KSTEP(aP, arP, 6, ) KSTEP(aP, arP, 7, )
    barrier_lgkm();
  }

#pragma unroll 1
  for (int s = 0; s < T_LEN - 1; ++s) {     // s = 0..1022
    // ======== interval B(s): MFMA(Q,s) + gates(P,s) + fin(P,s-1) ========
    {
      f32x4 xvP; XLOAD(xvP, 0, s);
      if (s > 0) { FIN(0, s-1, 0) }
      ACCZERO(aQ)
      f32x4 voP = zero4;
      KSTEP(aQ, arQ, 0, GEL(aP, hP, xvP, voP, 0, 0, 0))
      KSTEP(aQ, arQ, 1, GEL(aP, hP, xvP, voP, 0, 0, 1))
      KSTEP(aQ, arQ, 2, GEL(aP, hP, xvP, voP, 0, 0, 2))
      KSTEP(aQ, arQ, 3, GEL(aP, hP, xvP, voP, 0, 0, 3))
      KSTEP(aQ, arQ, 4, GEL(aP, hP, xvP, voP, 0, 1, 0))
      KSTEP(aQ, arQ, 5, GEL(aP, hP, xvP, voP, 0, 1, 1))
      KSTEP(aQ, arQ, 6, GEL(aP, hP, xvP, voP, 0, 1, 2))
      KSTEP(aQ, arQ, 7, GEL(aP, hP, xvP, voP, 0, 1, 3))
      VORED(voP, 0, s)
      barrier_lgkm();
    }
    // ======== interval A(s+1): MFMA(P,s+1) + gates(Q,s) + fin(Q,s-1) ========
    {
      f32x4 xvQ; XLOAD(xvQ, 1, s);
      if (s > 0) { FIN(1, s-1, 64) }
      ACCZERO(aP)
      f32x4 voQ = zero4;
      KSTEP(aP, arP, 0, GEL(aQ, hQ, xvQ, voQ, 1, 0, 0))
      KSTEP(aP, arP, 1, GEL(aQ, hQ, xvQ, voQ, 1, 0, 1))
      KSTEP(aP, arP, 2, GEL(aQ, hQ, xvQ, voQ, 1, 0, 2))
      KSTEP(aP, arP, 3, GEL(aQ, hQ, xvQ, voQ, 1, 0, 3))
      KSTEP(aP, arP, 4, GEL(aQ, hQ, xvQ, voQ, 1, 1, 0))
      KSTEP(aP, arP, 5, GEL(aQ, hQ, xvQ, voQ, 1, 1, 1))
      KSTEP(aP, arP, 6, GEL(aQ, hQ, xvQ, voQ, 1, 1, 2))
      KSTEP(aP, arP, 7, GEL(aQ, hQ, xvQ, voQ, 1, 1, 3))
      VORED(voQ, 1, s)
      barrier_lgkm();
    }
  }

  // ======== interval B(1023): MFMA(Q,1023) + gates(P,1023) + fin(P,1022) ========
  {
    const int s = T_LEN - 1;
    f32x4 xvP; XLOAD(xvP, 0, s);
    FIN(0, s-1, 0)
    ACCZERO(aQ)
    f32x4 voP = zero4;
    KSTEP(aQ, arQ, 0, GEL(aP, hP, xvP, voP, 0, 0, 0))
    KSTEP(aQ, arQ, 1, GEL(aP, hP, xvP, voP, 0, 0, 1))
    KSTEP(aQ, arQ, 2, GEL(aP, hP, xvP, voP, 0, 0, 2))
    KSTEP(aQ, arQ, 3, GEL(aP, hP, xvP, voP, 0, 0, 3))
    KSTEP(aQ, arQ, 4, GEL(aP, hP, xvP, voP, 0, 1, 0))
    KSTEP(aQ, arQ, 5, GEL(aP, hP, xvP, voP, 0, 1, 1))
    KSTEP(aQ, arQ, 6, GEL(aP, hP, xvP, voP, 0, 1, 2))
    KSTEP(aQ, arQ, 7, GEL(aP, hP, xvP, voP, 0, 1, 3))
    VORED(voP, 0, s)
    barrier_lgkm();
  }
  // ======== epilogue interval: gates(Q,1023) + fin(Q,1022) ========
  {
    const int s = T_LEN - 1;
    f32x4 xvQ; XLOAD(xvQ, 1, s);
    FIN(1, s-1, 64)
    f32x4 voQ = zero4;
    GEL(aQ, hQ, xvQ, voQ, 1, 0, 0)
    GEL(aQ, hQ, xvQ, voQ, 1, 0, 1)
    GEL(aQ, hQ, xvQ, voQ, 1, 0, 2)
    GEL(aQ, hQ, xvQ, voQ, 1, 0, 3)
    GEL(aQ, hQ, xvQ, voQ, 1, 1, 0)
    GEL(aQ, hQ, xvQ, voQ, 1, 1, 1)
    GEL(aQ, hQ, xvQ, voQ, 1, 1, 2)
    GEL(aQ, hQ, xvQ, voQ, 1, 1, 3)
    VORED(voQ, 1, s)
    barrier_lgkm();
  }
  // ======== final finalizes: (P,1023) and (Q,1023) ========
  FIN(0, T_LEN - 1, 0)
  FIN(1, T_LEN - 1, 64)
}

extern "C" void kernel_launch(void* const* d_in, const int* in_sizes, int n_in,
                              void* d_out, int out_size, void* d_ws, size_t ws_size,
                              hipStream_t stream) {
  const float* x     = (const float*)d_in[0];
  const float* w_ih  = (const float*)d_in[1];
  const float* w_hh  = (const float*)d_in[2];
  const float* b_ih  = (const float*)d_in[3];
  const float* b_hh  = (const float*)d_in[4];
  const float* w_out = (const float*)d_in[5];
  const float* b_out = (const float*)d_in[6];
  float* out = (float*)d_out;

  prep_w<<<768, 256, 0, stream>>>(w_hh);
  gru_kernel<<<NBLOCKS, NTHREADS, 0, stream>>>(x, w_ih, b_ih, b_hh, w_out, b_out, out);
}